// Round 5
// baseline (312.056 us; speedup 1.0000x reference)
//
#include <hip/hip_runtime.h>

typedef unsigned short u16;
typedef __attribute__((ext_vector_type(8))) short short8;
typedef __attribute__((ext_vector_type(4))) float floatx4;

#define MFMA16(a, b, c) __builtin_amdgcn_mfma_f32_16x16x32_bf16((a), (b), (c), 0, 0, 0)

// B=4, C=128, I=64, H=W=64, N=4096. Inputs/outputs fp32; intermediates bf16.
#define SZ_P ((size_t)4 * 64 * 4096)   // one projection / y buffer (elements)

__device__ __forceinline__ float bf2f(u16 u) {
    union { unsigned int i; float f; } v; v.i = ((unsigned int)u) << 16; return v.f;
}
__device__ __forceinline__ u16 f2bf(float f) {
    union { float f; unsigned int i; } v; v.f = f;
    unsigned int r = v.i + 0x7fffu + ((v.i >> 16) & 1u);
    return (u16)(r >> 16);
}
// pack 8 consecutive fp32 -> bf16x8 fragment
__device__ __forceinline__ short8 pack8(const float* __restrict__ p) {
    short8 r;
#pragma unroll
    for (int j = 0; j < 8; ++j) r[j] = (short)f2bf(p[j]);
    return r;
}

// ---------------------------------------------------------------------------
// K1: one branch's three projections (q=theta, k=phi, v=g). x fp32 [B,C,N];
// q,k out bf16 [B,N,I]; v out bf16 [B,I,N]. is_local: mask-gate q,k.
// ---------------------------------------------------------------------------
__global__ __launch_bounds__(256) void k_proj(
    const float* __restrict__ x, const float* __restrict__ mask,
    const float* __restrict__ wq, const float* __restrict__ bq,
    const float* __restrict__ wk, const float* __restrict__ bk,
    const float* __restrict__ wv, const float* __restrict__ bv,
    u16* __restrict__ q, u16* __restrict__ k, u16* __restrict__ v,
    int is_local)
{
    __shared__ __align__(16) u16 xt_s[64 * 136];  // [n][c] bf16, pad 128->136
    const int n0 = blockIdx.x * 64, b = blockIdx.y;
    const int t = threadIdx.x, wvi = t >> 6, lane = t & 63;
    const int quad = lane >> 4, l15 = lane & 15;
    const float* xb = x + ((size_t)b << 19);

    for (int idx = t; idx < 8192; idx += 256) {
        const int c = idx >> 6, n = idx & 63;
        xt_s[n * 136 + c] = f2bf(xb[((size_t)c << 12) + n0 + n]);
    }
    __syncthreads();

    short8 ax[4];
#pragma unroll
    for (int cc = 0; cc < 4; ++cc)
        ax[cc] = *(const short8*)&xt_s[(wvi * 16 + l15) * 136 + quad * 8 + cc * 32];

    float mv[4] = {1.f, 1.f, 1.f, 1.f};
    if (is_local) {
#pragma unroll
        for (int r = 0; r < 4; ++r)
            mv[r] = mask[((size_t)b << 12) + n0 + wvi * 16 + quad * 4 + r];
    }

    // Q and K: D[n][i]
#pragma unroll
    for (int qk = 0; qk < 2; ++qk) {
        const float* w = qk ? wk : wq;
        const float* bb = qk ? bk : bq;
        u16* o = qk ? k : q;
#pragma unroll
        for (int ns = 0; ns < 4; ++ns) {
            floatx4 acc = {0.f, 0.f, 0.f, 0.f};
            const float* wp = w + (ns * 16 + l15) * 128 + quad * 8;
#pragma unroll
            for (int cc = 0; cc < 4; ++cc)
                acc = MFMA16(ax[cc], pack8(wp + cc * 32), acc);
            const float bias_i = bb[ns * 16 + l15];
#pragma unroll
            for (int r = 0; r < 4; ++r) {
                const float val = (acc[r] + bias_i) * mv[r];
                o[((size_t)b << 18) + (size_t)(n0 + wvi * 16 + quad * 4 + r) * 64
                  + ns * 16 + l15] = f2bf(val);
            }
        }
    }

    // V: D[i][n]
    short8 aw[4];
#pragma unroll
    for (int cc = 0; cc < 4; ++cc)
        aw[cc] = pack8(wv + (wvi * 16 + l15) * 128 + quad * 8 + cc * 32);
    float bvr[4];
#pragma unroll
    for (int r = 0; r < 4; ++r) bvr[r] = bv[wvi * 16 + quad * 4 + r];
#pragma unroll
    for (int ns = 0; ns < 4; ++ns) {
        floatx4 acc = {0.f, 0.f, 0.f, 0.f};
#pragma unroll
        for (int cc = 0; cc < 4; ++cc)
            acc = MFMA16(aw[cc],
                *(const short8*)&xt_s[(ns * 16 + l15) * 136 + quad * 8 + cc * 32], acc);
#pragma unroll
        for (int r = 0; r < 4; ++r) {
            v[((size_t)b << 18) + ((size_t)(wvi * 16 + quad * 4 + r) << 12)
              + n0 + ns * 16 + l15] = f2bf(acc[r] + bvr[r]);
        }
    }
}

// ---------------------------------------------------------------------------
// K2: attention, one branch. Q,K bf16 [B,N,I]; V bf16 [B,I,N]; O bf16 [B,N,I].
// exp without max subtraction (bounded logits); denominator via ones-row MFMA
// (same path as numerator -> self-consistent normalization).
// ---------------------------------------------------------------------------
__global__ __launch_bounds__(256) void k_flash(
    const u16* __restrict__ Qg, const u16* __restrict__ Kg,
    const u16* __restrict__ Vg, u16* __restrict__ Og)
{
    __shared__ __align__(16) u16 kt_s[64 * 72];    // [key m][i]
    __shared__ __align__(16) u16 vt_s[80 * 72];    // rows 0..63: [i][key]; 64: ones; 65..79: zeros
    __shared__ __align__(16) u16 p_s[4 * 16 * 72]; // per-wave P [q][m]
    __shared__ float lred_s[4 * 16];

    const int q0 = blockIdx.x * 64, b = blockIdx.y;
    const size_t base = ((size_t)b << 18);
    const u16* Q = Qg + base;
    const u16* K = Kg + base;
    const u16* V = Vg + base;
    u16* O = Og + base;

    const int t = threadIdx.x, wvi = t >> 6, lane = t & 63;
    const int quad = lane >> 4, l15 = lane & 15;

    for (int idx = t; idx < 16 * 64; idx += 256) {
        const int row = 64 + (idx >> 6), col = idx & 63;
        vt_s[row * 72 + col] = (row == 64) ? (u16)0x3F80 : (u16)0;
    }

    short8 aq[2];
    {
        const u16* qp = Q + (size_t)(q0 + wvi * 16 + l15) * 64 + quad * 8;
        aq[0] = *(const short8*)qp;
        aq[1] = *(const short8*)(qp + 32);
    }

    floatx4 oacc[4];
    floatx4 lacc = {0.f, 0.f, 0.f, 0.f};
#pragma unroll
    for (int i = 0; i < 4; ++i) oacc[i] = (floatx4){0.f, 0.f, 0.f, 0.f};

    const int pb = wvi * 16 * 72;

    for (int m0 = 0; m0 < 4096; m0 += 64) {
#pragma unroll
        for (int ch = t; ch < 512; ch += 256) {
            const int row = ch >> 3, cg = ch & 7;
            *(short8*)&kt_s[row * 72 + cg * 8] =
                *(const short8*)(K + (size_t)(m0 + row) * 64 + cg * 8);
            *(short8*)&vt_s[row * 72 + cg * 8] =
                *(const short8*)(V + ((size_t)row << 12) + m0 + cg * 8);
        }
        __syncthreads();

        floatx4 s[4];
#pragma unroll
        for (int ms = 0; ms < 4; ++ms) {
            floatx4 acc = {0.f, 0.f, 0.f, 0.f};
            const u16* kp = &kt_s[(ms * 16 + l15) * 72 + quad * 8];
            acc = MFMA16(aq[0], *(const short8*)kp, acc);
            acc = MFMA16(aq[1], *(const short8*)(kp + 32), acc);
            s[ms] = acc;
        }

#pragma unroll
        for (int ms = 0; ms < 4; ++ms)
#pragma unroll
            for (int r = 0; r < 4; ++r)
                p_s[pb + (quad * 4 + r) * 72 + ms * 16 + l15] = f2bf(__expf(s[ms][r]));
        __syncthreads();

        short8 ap0 = *(const short8*)&p_s[pb + l15 * 72 + quad * 8];
        short8 ap1 = *(const short8*)&p_s[pb + l15 * 72 + 32 + quad * 8];
#pragma unroll
        for (int is = 0; is < 4; ++is) {
            const u16* vp = &vt_s[(is * 16 + l15) * 72 + quad * 8];
            oacc[is] = MFMA16(ap0, *(const short8*)vp, oacc[is]);
            oacc[is] = MFMA16(ap1, *(const short8*)(vp + 32), oacc[is]);
        }
        {
            const u16* vp4 = &vt_s[(64 + l15) * 72 + quad * 8];
            lacc = MFMA16(ap0, *(const short8*)vp4, lacc);
            lacc = MFMA16(ap1, *(const short8*)(vp4 + 32), lacc);
        }
        __syncthreads();
    }

    if (l15 == 0) {
#pragma unroll
        for (int r = 0; r < 4; ++r) lred_s[wvi * 16 + quad * 4 + r] = lacc[r];
    }
    __syncthreads();

    float inv[4];
#pragma unroll
    for (int r = 0; r < 4; ++r) inv[r] = 1.0f / lred_s[wvi * 16 + quad * 4 + r];
#pragma unroll
    for (int is = 0; is < 4; ++is)
#pragma unroll
        for (int r = 0; r < 4; ++r) {
            const int n = q0 + wvi * 16 + quad * 4 + r;
            O[(size_t)n * 64 + is * 16 + l15] = f2bf(oacc[is][r] * inv[r]);
        }
}

// ---------------------------------------------------------------------------
// K3: fused epilogue. y bufs bf16; weights/x/out fp32.
//   yy[n][io] = bnWl(relu(wWl . y_l)) + y_nl
//   out[c][n] = bnW(relu(wW . yy + bW)) + x
// ---------------------------------------------------------------------------
__global__ __launch_bounds__(256) void k_epi(
    const u16* __restrict__ ytl, const u16* __restrict__ ytnl,
    const float* __restrict__ wWl, const float* __restrict__ gWl, const float* __restrict__ betaWl,
    const float* __restrict__ wW, const float* __restrict__ bW,
    const float* __restrict__ gW, const float* __restrict__ betaW,
    const float* __restrict__ x, float* __restrict__ out)
{
    __shared__ __align__(16) u16 yl_s[64 * 72];
    __shared__ __align__(16) u16 ynl_s[64 * 72];
    __shared__ __align__(16) u16 yy_s[64 * 72];
    const int b = blockIdx.y, n0 = blockIdx.x * 64;
    const int t = threadIdx.x, wvi = t >> 6, lane = t & 63;
    const int quad = lane >> 4, l15 = lane & 15;
    const size_t ybase = ((size_t)b << 18) + (size_t)n0 * 64;

#pragma unroll
    for (int ch = t; ch < 512; ch += 256) {
        const int row = ch >> 3, cg = ch & 7;
        *(short8*)&yl_s[row * 72 + cg * 8] =
            *(const short8*)(ytl + ybase + row * 64 + cg * 8);
        *(short8*)&ynl_s[row * 72 + cg * 8] =
            *(const short8*)(ytnl + ybase + row * 64 + cg * 8);
    }
    __syncthreads();
    const float rsq = rsqrtf(1.0f + 1e-5f);

    // E1
    {
        const short8 a0 = pack8(wWl + (wvi * 16 + l15) * 64 + quad * 8);
        const short8 a1 = pack8(wWl + (wvi * 16 + l15) * 64 + 32 + quad * 8);
        float sc[4], bt[4];
#pragma unroll
        for (int r = 0; r < 4; ++r) {
            const int io = wvi * 16 + quad * 4 + r;
            sc[r] = gWl[io] * rsq;
            bt[r] = betaWl[io];
        }
#pragma unroll
        for (int ns = 0; ns < 4; ++ns) {
            floatx4 acc = {0.f, 0.f, 0.f, 0.f};
            const u16* bp_ = &yl_s[(ns * 16 + l15) * 72 + quad * 8];
            acc = MFMA16(a0, *(const short8*)bp_, acc);
            acc = MFMA16(a1, *(const short8*)(bp_ + 32), acc);
#pragma unroll
            for (int r = 0; r < 4; ++r) {
                const int io = wvi * 16 + quad * 4 + r;
                float val = fmaxf(acc[r], 0.f) * sc[r] + bt[r];
                val += bf2f(ynl_s[(ns * 16 + l15) * 72 + io]);
                yy_s[(ns * 16 + l15) * 72 + io] = f2bf(val);
            }
        }
    }
    __syncthreads();

    // E2
#pragma unroll
    for (int rb = 0; rb < 2; ++rb) {
        const int c0 = rb * 64 + wvi * 16;
        const short8 a0 = pack8(wW + (c0 + l15) * 64 + quad * 8);
        const short8 a1 = pack8(wW + (c0 + l15) * 64 + 32 + quad * 8);
        float bs[4], sc[4], bt[4];
#pragma unroll
        for (int r = 0; r < 4; ++r) {
            const int c = c0 + quad * 4 + r;
            bs[r] = bW[c];
            sc[r] = gW[c] * rsq;
            bt[r] = betaW[c];
        }
#pragma unroll
        for (int ns = 0; ns < 4; ++ns) {
            floatx4 acc = {0.f, 0.f, 0.f, 0.f};
            const u16* bp_ = &yy_s[(ns * 16 + l15) * 72 + quad * 8];
            acc = MFMA16(a0, *(const short8*)bp_, acc);
            acc = MFMA16(a1, *(const short8*)(bp_ + 32), acc);
#pragma unroll
            for (int r = 0; r < 4; ++r) {
                const int c = c0 + quad * 4 + r;
                float val = fmaxf(acc[r] + bs[r], 0.f) * sc[r] + bt[r];
                const size_t xi = ((size_t)b << 19) + ((size_t)c << 12) + n0 + ns * 16 + l15;
                out[xi] = val + x[xi];
            }
        }
    }
}

// ---------------------------------------------------------------------------
extern "C" void kernel_launch(void* const* d_in, const int* in_sizes, int n_in,
                              void* d_out, int out_size, void* d_ws, size_t ws_size,
                              hipStream_t stream) {
    const float* x      = (const float*)d_in[0];
    const float* mask   = (const float*)d_in[1];
    const float* wt_nl  = (const float*)d_in[2];  const float* bt_nl = (const float*)d_in[3];
    const float* wp_nl  = (const float*)d_in[4];  const float* bp_nl = (const float*)d_in[5];
    const float* wt_l   = (const float*)d_in[6];  const float* bt_l  = (const float*)d_in[7];
    const float* wp_l   = (const float*)d_in[8];  const float* bp_l  = (const float*)d_in[9];
    const float* wg_nl  = (const float*)d_in[10]; const float* bg_nl = (const float*)d_in[11];
    const float* wg_l   = (const float*)d_in[12]; const float* bg_l  = (const float*)d_in[13];
    const float* wW     = (const float*)d_in[14]; const float* bW    = (const float*)d_in[15];
    const float* gW     = (const float*)d_in[16]; const float* betaW = (const float*)d_in[17];
    const float* wWl    = (const float*)d_in[18]; const float* gWl   = (const float*)d_in[19];
    const float* betaWl = (const float*)d_in[20];

    // workspace: 5 x SZ_P bf16 buffers = 10.49 MB
    u16* ws  = (u16*)d_ws;
    u16* q   = ws;            // [B,N,I]
    u16* k   = q + SZ_P;      // [B,N,I]
    u16* v   = k + SZ_P;      // [B,I,N]
    u16* ynl = v + SZ_P;      // [B,N,I]
    u16* yl  = ynl + SZ_P;    // [B,N,I]

    // non-local branch
    k_proj<<<dim3(64, 4), 256, 0, stream>>>(x, mask, wt_nl, bt_nl, wp_nl, bp_nl,
                                            wg_nl, bg_nl, q, k, v, 0);
    k_flash<<<dim3(64, 4), 256, 0, stream>>>(q, k, v, ynl);
    // local branch (reuses q,k,v)
    k_proj<<<dim3(64, 4), 256, 0, stream>>>(x, mask, wt_l, bt_l, wp_l, bp_l,
                                            wg_l, bg_l, q, k, v, 1);
    k_flash<<<dim3(64, 4), 256, 0, stream>>>(q, k, v, yl);
    // epilogue
    k_epi<<<dim3(64, 4), 256, 0, stream>>>(yl, ynl, wWl, gWl, betaWl,
                                           wW, bW, gW, betaW, x, (float*)d_out);
}

// Round 6
// 223.720 us; speedup vs baseline: 1.3949x; 1.3949x over previous
//
#include <hip/hip_runtime.h>

typedef unsigned short u16;
typedef __attribute__((ext_vector_type(8))) short short8;
typedef __attribute__((ext_vector_type(4))) float floatx4;

#define MFMA16(a, b, c) __builtin_amdgcn_mfma_f32_16x16x32_bf16((a), (b), (c), 0, 0, 0)

// B=4, C=128, I=64, H=W=64, N=4096. fp32 I/O; bf16 intermediates.
#define SZ_P ((size_t)4 * 64 * 4096)   // one projection / y buffer (elements)

__device__ __forceinline__ float bf2f(u16 u) {
    union { unsigned int i; float f; } v; v.i = ((unsigned int)u) << 16; return v.f;
}
__device__ __forceinline__ u16 f2bf(float f) {
    union { float f; unsigned int i; } v; v.f = f;
    unsigned int r = v.i + 0x7fffu + ((v.i >> 16) & 1u);
    return (u16)(r >> 16);
}
__device__ __forceinline__ short8 pack8(const float* __restrict__ p) {
    short8 r;
#pragma unroll
    for (int j = 0; j < 8; ++j) r[j] = (short)f2bf(p[j]);
    return r;
}

// ---------------------------------------------------------------------------
// K1: both branches' projections in ONE dispatch (z = branch).
// x fp32 [B,C,N]; q,k bf16 [B,N,I]; v bf16 [B,I,N]. local branch mask-gates q,k.
// ---------------------------------------------------------------------------
__global__ __launch_bounds__(256) void k_proj(
    const float* __restrict__ x, const float* __restrict__ mask,
    const float* __restrict__ wq0, const float* __restrict__ bq0,
    const float* __restrict__ wk0, const float* __restrict__ bk0,
    const float* __restrict__ wv0, const float* __restrict__ bv0,
    const float* __restrict__ wq1, const float* __restrict__ bq1,
    const float* __restrict__ wk1, const float* __restrict__ bk1,
    const float* __restrict__ wv1, const float* __restrict__ bv1,
    u16* __restrict__ q0, u16* __restrict__ k0, u16* __restrict__ v0,
    u16* __restrict__ q1, u16* __restrict__ k1, u16* __restrict__ v1)
{
    __shared__ __align__(16) u16 xt_s[64 * 136];  // [n][c] bf16, pad 128->136
    const int n0 = blockIdx.x * 64, b = blockIdx.y, br = blockIdx.z;
    const float* wq = br ? wq1 : wq0;  const float* bq = br ? bq1 : bq0;
    const float* wk = br ? wk1 : wk0;  const float* bk = br ? bk1 : bk0;
    const float* wv = br ? wv1 : wv0;  const float* bv = br ? bv1 : bv0;
    u16* q = br ? q1 : q0;  u16* k = br ? k1 : k0;  u16* v = br ? v1 : v0;

    const int t = threadIdx.x, wvi = t >> 6, lane = t & 63;
    const int quad = lane >> 4, l15 = lane & 15;
    const float* xb = x + ((size_t)b << 19);

    for (int idx = t; idx < 8192; idx += 256) {
        const int c = idx >> 6, n = idx & 63;
        xt_s[n * 136 + c] = f2bf(xb[((size_t)c << 12) + n0 + n]);
    }
    __syncthreads();

    short8 ax[4];
#pragma unroll
    for (int cc = 0; cc < 4; ++cc)
        ax[cc] = *(const short8*)&xt_s[(wvi * 16 + l15) * 136 + quad * 8 + cc * 32];

    float mv[4] = {1.f, 1.f, 1.f, 1.f};
    if (br) {
#pragma unroll
        for (int r = 0; r < 4; ++r)
            mv[r] = mask[((size_t)b << 12) + n0 + wvi * 16 + quad * 4 + r];
    }

    // Q and K: D[n][i]
#pragma unroll
    for (int qk = 0; qk < 2; ++qk) {
        const float* w = qk ? wk : wq;
        const float* bb = qk ? bk : bq;
        u16* o = qk ? k : q;
#pragma unroll
        for (int ns = 0; ns < 4; ++ns) {
            floatx4 acc = {0.f, 0.f, 0.f, 0.f};
            const float* wp = w + (ns * 16 + l15) * 128 + quad * 8;
#pragma unroll
            for (int cc = 0; cc < 4; ++cc)
                acc = MFMA16(ax[cc], pack8(wp + cc * 32), acc);
            const float bias_i = bb[ns * 16 + l15];
#pragma unroll
            for (int r = 0; r < 4; ++r) {
                const float val = (acc[r] + bias_i) * mv[r];
                o[((size_t)b << 18) + (size_t)(n0 + wvi * 16 + quad * 4 + r) * 64
                  + ns * 16 + l15] = f2bf(val);
            }
        }
    }

    // V: D[i][n]
    short8 aw[4];
#pragma unroll
    for (int cc = 0; cc < 4; ++cc)
        aw[cc] = pack8(wv + (wvi * 16 + l15) * 128 + quad * 8 + cc * 32);
    float bvr[4];
#pragma unroll
    for (int r = 0; r < 4; ++r) bvr[r] = bv[wvi * 16 + quad * 4 + r];
#pragma unroll
    for (int ns = 0; ns < 4; ++ns) {
        floatx4 acc = {0.f, 0.f, 0.f, 0.f};
#pragma unroll
        for (int cc = 0; cc < 4; ++cc)
            acc = MFMA16(aw[cc],
                *(const short8*)&xt_s[(ns * 16 + l15) * 136 + quad * 8 + cc * 32], acc);
#pragma unroll
        for (int r = 0; r < 4; ++r) {
            v[((size_t)b << 18) + ((size_t)(wvi * 16 + quad * 4 + r) << 12)
              + n0 + ns * 16 + l15] = f2bf(acc[r] + bvr[r]);
        }
    }
}

// ---------------------------------------------------------------------------
// K2: attention, BOTH branches in one dispatch (z = branch).
// Q,K bf16 [B,N,I]; V bf16 [B,I,N]; O bf16 [B,N,I]. exp w/o max subtraction
// (bounded logits); denominator via ones-row MFMA (self-consistent norm).
// ---------------------------------------------------------------------------
__global__ __launch_bounds__(256) void k_flash(
    const u16* __restrict__ Q0, const u16* __restrict__ K0,
    const u16* __restrict__ V0, u16* __restrict__ O0,
    const u16* __restrict__ Q1, const u16* __restrict__ K1,
    const u16* __restrict__ V1, u16* __restrict__ O1)
{
    __shared__ __align__(16) u16 kt_s[64 * 72];    // [key m][i]
    __shared__ __align__(16) u16 vt_s[80 * 72];    // 0..63: [i][key]; 64: ones; 65..79: zeros
    __shared__ __align__(16) u16 p_s[4 * 16 * 72]; // per-wave P [q][m]
    __shared__ float lred_s[4 * 16];

    const int q0 = blockIdx.x * 64, b = blockIdx.y, br = blockIdx.z;
    const size_t base = ((size_t)b << 18);
    const u16* Q = (br ? Q1 : Q0) + base;
    const u16* K = (br ? K1 : K0) + base;
    const u16* V = (br ? V1 : V0) + base;
    u16* O = (br ? O1 : O0) + base;

    const int t = threadIdx.x, wvi = t >> 6, lane = t & 63;
    const int quad = lane >> 4, l15 = lane & 15;

    for (int idx = t; idx < 16 * 64; idx += 256) {
        const int row = 64 + (idx >> 6), col = idx & 63;
        vt_s[row * 72 + col] = (row == 64) ? (u16)0x3F80 : (u16)0;
    }

    short8 aq[2];
    {
        const u16* qp = Q + (size_t)(q0 + wvi * 16 + l15) * 64 + quad * 8;
        aq[0] = *(const short8*)qp;
        aq[1] = *(const short8*)(qp + 32);
    }

    floatx4 oacc[4];
    floatx4 lacc = {0.f, 0.f, 0.f, 0.f};
#pragma unroll
    for (int i = 0; i < 4; ++i) oacc[i] = (floatx4){0.f, 0.f, 0.f, 0.f};

    const int pb = wvi * 16 * 72;

    for (int m0 = 0; m0 < 4096; m0 += 64) {
#pragma unroll
        for (int ch = t; ch < 512; ch += 256) {
            const int row = ch >> 3, cg = ch & 7;
            *(short8*)&kt_s[row * 72 + cg * 8] =
                *(const short8*)(K + (size_t)(m0 + row) * 64 + cg * 8);
            *(short8*)&vt_s[row * 72 + cg * 8] =
                *(const short8*)(V + ((size_t)row << 12) + m0 + cg * 8);
        }
        __syncthreads();

        floatx4 s[4];
#pragma unroll
        for (int ms = 0; ms < 4; ++ms) {
            floatx4 acc = {0.f, 0.f, 0.f, 0.f};
            const u16* kp = &kt_s[(ms * 16 + l15) * 72 + quad * 8];
            acc = MFMA16(aq[0], *(const short8*)kp, acc);
            acc = MFMA16(aq[1], *(const short8*)(kp + 32), acc);
            s[ms] = acc;
        }

#pragma unroll
        for (int ms = 0; ms < 4; ++ms)
#pragma unroll
            for (int r = 0; r < 4; ++r)
                p_s[pb + (quad * 4 + r) * 72 + ms * 16 + l15] = f2bf(__expf(s[ms][r]));
        __syncthreads();

        short8 ap0 = *(const short8*)&p_s[pb + l15 * 72 + quad * 8];
        short8 ap1 = *(const short8*)&p_s[pb + l15 * 72 + 32 + quad * 8];
#pragma unroll
        for (int is = 0; is < 4; ++is) {
            const u16* vp = &vt_s[(is * 16 + l15) * 72 + quad * 8];
            oacc[is] = MFMA16(ap0, *(const short8*)vp, oacc[is]);
            oacc[is] = MFMA16(ap1, *(const short8*)(vp + 32), oacc[is]);
        }
        {
            const u16* vp4 = &vt_s[(64 + l15) * 72 + quad * 8];
            lacc = MFMA16(ap0, *(const short8*)vp4, lacc);
            lacc = MFMA16(ap1, *(const short8*)(vp4 + 32), lacc);
        }
        __syncthreads();
    }

    if (l15 == 0) {
#pragma unroll
        for (int r = 0; r < 4; ++r) lred_s[wvi * 16 + quad * 4 + r] = lacc[r];
    }
    __syncthreads();

    float inv[4];
#pragma unroll
    for (int r = 0; r < 4; ++r) inv[r] = 1.0f / lred_s[wvi * 16 + quad * 4 + r];
#pragma unroll
    for (int is = 0; is < 4; ++is)
#pragma unroll
        for (int r = 0; r < 4; ++r) {
            const int n = q0 + wvi * 16 + quad * 4 + r;
            O[(size_t)n * 64 + is * 16 + l15] = f2bf(oacc[is][r] * inv[r]);
        }
}

// ---------------------------------------------------------------------------
// K3: fused epilogue, z splits the E2 c-range (each half redoes cheap E1).
//   yy[n][io] = bnWl(relu(wWl . y_l)) + y_nl
//   out[c][n] = bnW(relu(wW . yy + bW)) + x
// ---------------------------------------------------------------------------
__global__ __launch_bounds__(256) void k_epi(
    const u16* __restrict__ ytl, const u16* __restrict__ ytnl,
    const float* __restrict__ wWl, const float* __restrict__ gWl, const float* __restrict__ betaWl,
    const float* __restrict__ wW, const float* __restrict__ bW,
    const float* __restrict__ gW, const float* __restrict__ betaW,
    const float* __restrict__ x, float* __restrict__ out)
{
    __shared__ __align__(16) u16 yl_s[64 * 72];
    __shared__ __align__(16) u16 ynl_s[64 * 72];
    __shared__ __align__(16) u16 yy_s[64 * 72];
    const int b = blockIdx.y, n0 = blockIdx.x * 64, rb = blockIdx.z;
    const int t = threadIdx.x, wvi = t >> 6, lane = t & 63;
    const int quad = lane >> 4, l15 = lane & 15;
    const size_t ybase = ((size_t)b << 18) + (size_t)n0 * 64;

#pragma unroll
    for (int ch = t; ch < 512; ch += 256) {
        const int row = ch >> 3, cg = ch & 7;
        *(short8*)&yl_s[row * 72 + cg * 8] =
            *(const short8*)(ytl + ybase + row * 64 + cg * 8);
        *(short8*)&ynl_s[row * 72 + cg * 8] =
            *(const short8*)(ytnl + ybase + row * 64 + cg * 8);
    }
    __syncthreads();
    const float rsq = rsqrtf(1.0f + 1e-5f);

    // E1 (both z-halves compute it; 8 MFMAs)
    {
        const short8 a0 = pack8(wWl + (wvi * 16 + l15) * 64 + quad * 8);
        const short8 a1 = pack8(wWl + (wvi * 16 + l15) * 64 + 32 + quad * 8);
        float sc[4], bt[4];
#pragma unroll
        for (int r = 0; r < 4; ++r) {
            const int io = wvi * 16 + quad * 4 + r;
            sc[r] = gWl[io] * rsq;
            bt[r] = betaWl[io];
        }
#pragma unroll
        for (int ns = 0; ns < 4; ++ns) {
            floatx4 acc = {0.f, 0.f, 0.f, 0.f};
            const u16* bp_ = &yl_s[(ns * 16 + l15) * 72 + quad * 8];
            acc = MFMA16(a0, *(const short8*)bp_, acc);
            acc = MFMA16(a1, *(const short8*)(bp_ + 32), acc);
#pragma unroll
            for (int r = 0; r < 4; ++r) {
                const int io = wvi * 16 + quad * 4 + r;
                float val = fmaxf(acc[r], 0.f) * sc[r] + bt[r];
                val += bf2f(ynl_s[(ns * 16 + l15) * 72 + io]);
                yy_s[(ns * 16 + l15) * 72 + io] = f2bf(val);
            }
        }
    }
    __syncthreads();

    // E2: this block's half of the c-range
    {
        const int c0 = rb * 64 + wvi * 16;
        const short8 a0 = pack8(wW + (c0 + l15) * 64 + quad * 8);
        const short8 a1 = pack8(wW + (c0 + l15) * 64 + 32 + quad * 8);
        float bs[4], sc[4], bt[4];
#pragma unroll
        for (int r = 0; r < 4; ++r) {
            const int c = c0 + quad * 4 + r;
            bs[r] = bW[c];
            sc[r] = gW[c] * rsq;
            bt[r] = betaW[c];
        }
#pragma unroll
        for (int ns = 0; ns < 4; ++ns) {
            floatx4 acc = {0.f, 0.f, 0.f, 0.f};
            const u16* bp_ = &yy_s[(ns * 16 + l15) * 72 + quad * 8];
            acc = MFMA16(a0, *(const short8*)bp_, acc);
            acc = MFMA16(a1, *(const short8*)(bp_ + 32), acc);
#pragma unroll
            for (int r = 0; r < 4; ++r) {
                const int c = c0 + quad * 4 + r;
                float val = fmaxf(acc[r] + bs[r], 0.f) * sc[r] + bt[r];
                const size_t xi = ((size_t)b << 19) + ((size_t)c << 12) + n0 + ns * 16 + l15;
                out[xi] = val + x[xi];
            }
        }
    }
}

// ---------------------------------------------------------------------------
extern "C" void kernel_launch(void* const* d_in, const int* in_sizes, int n_in,
                              void* d_out, int out_size, void* d_ws, size_t ws_size,
                              hipStream_t stream) {
    const float* x      = (const float*)d_in[0];
    const float* mask   = (const float*)d_in[1];
    const float* wt_nl  = (const float*)d_in[2];  const float* bt_nl = (const float*)d_in[3];
    const float* wp_nl  = (const float*)d_in[4];  const float* bp_nl = (const float*)d_in[5];
    const float* wt_l   = (const float*)d_in[6];  const float* bt_l  = (const float*)d_in[7];
    const float* wp_l   = (const float*)d_in[8];  const float* bp_l  = (const float*)d_in[9];
    const float* wg_nl  = (const float*)d_in[10]; const float* bg_nl = (const float*)d_in[11];
    const float* wg_l   = (const float*)d_in[12]; const float* bg_l  = (const float*)d_in[13];
    const float* wW     = (const float*)d_in[14]; const float* bW    = (const float*)d_in[15];
    const float* gW     = (const float*)d_in[16]; const float* betaW = (const float*)d_in[17];
    const float* wWl    = (const float*)d_in[18]; const float* gWl   = (const float*)d_in[19];
    const float* betaWl = (const float*)d_in[20];

    // workspace: 8 x SZ_P bf16 buffers = 16.78 MB
    u16* ws  = (u16*)d_ws;
    u16* q0  = ws;            // nl: [B,N,I]
    u16* k0  = q0 + SZ_P;
    u16* v0  = k0 + SZ_P;     // [B,I,N]
    u16* q1  = v0 + SZ_P;     // l
    u16* k1  = q1 + SZ_P;
    u16* v1  = k1 + SZ_P;
    u16* ynl = v1 + SZ_P;     // [B,N,I]
    u16* yl  = ynl + SZ_P;

    k_proj<<<dim3(64, 4, 2), 256, 0, stream>>>(x, mask,
        wt_nl, bt_nl, wp_nl, bp_nl, wg_nl, bg_nl,
        wt_l,  bt_l,  wp_l,  bp_l,  wg_l,  bg_l,
        q0, k0, v0, q1, k1, v1);
    k_flash<<<dim3(64, 4, 2), 256, 0, stream>>>(q0, k0, v0, ynl, q1, k1, v1, yl);
    k_epi<<<dim3(64, 4, 2), 256, 0, stream>>>(yl, ynl, wWl, gWl, betaWl,
                                              wW, bW, gW, betaW, x, (float*)d_out);
}

// Round 7
// 198.423 us; speedup vs baseline: 1.5727x; 1.1275x over previous
//
#include <hip/hip_runtime.h>

typedef unsigned short u16;
typedef __attribute__((ext_vector_type(8))) short short8;
typedef __attribute__((ext_vector_type(4))) float floatx4;

#define MFMA16(a, b, c) __builtin_amdgcn_mfma_f32_16x16x32_bf16((a), (b), (c), 0, 0, 0)

// B=4, C=128, I=64, H=W=64, N=4096. fp32 I/O; bf16 intermediates.
#define SZ_P ((size_t)4 * 64 * 4096)   // one projection buffer (elements)

__device__ __forceinline__ float bf2f(u16 u) {
    union { unsigned int i; float f; } v; v.i = ((unsigned int)u) << 16; return v.f;
}
__device__ __forceinline__ u16 f2bf(float f) {
    union { float f; unsigned int i; } v; v.f = f;
    unsigned int r = v.i + 0x7fffu + ((v.i >> 16) & 1u);
    return (u16)(r >> 16);
}
__device__ __forceinline__ short8 pack8(const float* __restrict__ p) {
    short8 r;
#pragma unroll
    for (int j = 0; j < 8; ++j) r[j] = (short)f2bf(p[j]);
    return r;
}

// ---------------------------------------------------------------------------
// K1: both branches' projections in ONE dispatch (z = branch).
// x fp32 [B,C,N]; q,k bf16 [B,N,I]; v bf16 [B,I,N]. local branch mask-gates q,k.
// ---------------------------------------------------------------------------
__global__ __launch_bounds__(256) void k_proj(
    const float* __restrict__ x, const float* __restrict__ mask,
    const float* __restrict__ wq0, const float* __restrict__ bq0,
    const float* __restrict__ wk0, const float* __restrict__ bk0,
    const float* __restrict__ wv0, const float* __restrict__ bv0,
    const float* __restrict__ wq1, const float* __restrict__ bq1,
    const float* __restrict__ wk1, const float* __restrict__ bk1,
    const float* __restrict__ wv1, const float* __restrict__ bv1,
    u16* __restrict__ q0, u16* __restrict__ k0, u16* __restrict__ v0,
    u16* __restrict__ q1, u16* __restrict__ k1, u16* __restrict__ v1)
{
    __shared__ __align__(16) u16 xt_s[64 * 136];  // [n][c] bf16, pad 128->136
    const int n0 = blockIdx.x * 64, b = blockIdx.y, br = blockIdx.z;
    const float* wq = br ? wq1 : wq0;  const float* bq = br ? bq1 : bq0;
    const float* wk = br ? wk1 : wk0;  const float* bk = br ? bk1 : bk0;
    const float* wv = br ? wv1 : wv0;  const float* bv = br ? bv1 : bv0;
    u16* q = br ? q1 : q0;  u16* k = br ? k1 : k0;  u16* v = br ? v1 : v0;

    const int t = threadIdx.x, wvi = t >> 6, lane = t & 63;
    const int quad = lane >> 4, l15 = lane & 15;
    const float* xb = x + ((size_t)b << 19);

    for (int idx = t; idx < 8192; idx += 256) {
        const int c = idx >> 6, n = idx & 63;
        xt_s[n * 136 + c] = f2bf(xb[((size_t)c << 12) + n0 + n]);
    }
    __syncthreads();

    short8 ax[4];
#pragma unroll
    for (int cc = 0; cc < 4; ++cc)
        ax[cc] = *(const short8*)&xt_s[(wvi * 16 + l15) * 136 + quad * 8 + cc * 32];

    float mv[4] = {1.f, 1.f, 1.f, 1.f};
    if (br) {
#pragma unroll
        for (int r = 0; r < 4; ++r)
            mv[r] = mask[((size_t)b << 12) + n0 + wvi * 16 + quad * 4 + r];
    }

    // Q and K: D[n][i]
#pragma unroll
    for (int qk = 0; qk < 2; ++qk) {
        const float* w = qk ? wk : wq;
        const float* bb = qk ? bk : bq;
        u16* o = qk ? k : q;
#pragma unroll
        for (int ns = 0; ns < 4; ++ns) {
            floatx4 acc = {0.f, 0.f, 0.f, 0.f};
            const float* wp = w + (ns * 16 + l15) * 128 + quad * 8;
#pragma unroll
            for (int cc = 0; cc < 4; ++cc)
                acc = MFMA16(ax[cc], pack8(wp + cc * 32), acc);
            const float bias_i = bb[ns * 16 + l15];
#pragma unroll
            for (int r = 0; r < 4; ++r) {
                const float val = (acc[r] + bias_i) * mv[r];
                o[((size_t)b << 18) + (size_t)(n0 + wvi * 16 + quad * 4 + r) * 64
                  + ns * 16 + l15] = f2bf(val);
            }
        }
    }

    // V: D[i][n]
    short8 aw[4];
#pragma unroll
    for (int cc = 0; cc < 4; ++cc)
        aw[cc] = pack8(wv + (wvi * 16 + l15) * 128 + quad * 8 + cc * 32);
    float bvr[4];
#pragma unroll
    for (int r = 0; r < 4; ++r) bvr[r] = bv[wvi * 16 + quad * 4 + r];
#pragma unroll
    for (int ns = 0; ns < 4; ++ns) {
        floatx4 acc = {0.f, 0.f, 0.f, 0.f};
#pragma unroll
        for (int cc = 0; cc < 4; ++cc)
            acc = MFMA16(aw[cc],
                *(const short8*)&xt_s[(ns * 16 + l15) * 136 + quad * 8 + cc * 32], acc);
#pragma unroll
        for (int r = 0; r < 4; ++r) {
            v[((size_t)b << 18) + ((size_t)(wvi * 16 + quad * 4 + r) << 12)
              + n0 + ns * 16 + l15] = f2bf(acc[r] + bvr[r]);
        }
    }
}

// ---------------------------------------------------------------------------
// K2: attention with split-K over keys (z = br*2+split). Absolute exp (no
// running max; logits bounded) makes split partials purely additive:
// num[z] = sum_m P V, den[z] = sum_m P (ones-row MFMA). No normalization here.
// ---------------------------------------------------------------------------
__global__ __launch_bounds__(256) void k_flash(
    const u16* __restrict__ Q0, const u16* __restrict__ K0,
    const u16* __restrict__ V0,
    const u16* __restrict__ Q1, const u16* __restrict__ K1,
    const u16* __restrict__ V1,
    u16* __restrict__ num, float* __restrict__ den)
{
    __shared__ __align__(16) u16 kt_s[64 * 72];    // [key m][i]
    __shared__ __align__(16) u16 vt_s[80 * 72];    // 0..63: [i][key]; 64: ones; 65..79: zeros
    __shared__ __align__(16) u16 p_s[4 * 16 * 72]; // per-wave P [q][m]

    const int q0 = blockIdx.x * 64, b = blockIdx.y, z = blockIdx.z;
    const int br = z >> 1, sp = z & 1;
    const size_t base = ((size_t)b << 18);
    const u16* Q = (br ? Q1 : Q0) + base;
    const u16* K = (br ? K1 : K0) + base;
    const u16* V = (br ? V1 : V0) + base;
    u16* numo = num + (size_t)z * SZ_P + base;     // [b][n][i] bf16
    float* deno = den + z * 16384 + b * 4096;      // [b][n] fp32

    const int t = threadIdx.x, wvi = t >> 6, lane = t & 63;
    const int quad = lane >> 4, l15 = lane & 15;

    for (int idx = t; idx < 16 * 64; idx += 256) {
        const int row = 64 + (idx >> 6), col = idx & 63;
        vt_s[row * 72 + col] = (row == 64) ? (u16)0x3F80 : (u16)0;
    }

    short8 aq[2];
    {
        const u16* qp = Q + (size_t)(q0 + wvi * 16 + l15) * 64 + quad * 8;
        aq[0] = *(const short8*)qp;
        aq[1] = *(const short8*)(qp + 32);
    }

    floatx4 oacc[4];
    floatx4 lacc = {0.f, 0.f, 0.f, 0.f};
#pragma unroll
    for (int i = 0; i < 4; ++i) oacc[i] = (floatx4){0.f, 0.f, 0.f, 0.f};

    const int pb = wvi * 16 * 72;
    const int m_beg = sp * 2048, m_end = m_beg + 2048;

    for (int m0 = m_beg; m0 < m_end; m0 += 64) {
#pragma unroll
        for (int ch = t; ch < 512; ch += 256) {
            const int row = ch >> 3, cg = ch & 7;
            *(short8*)&kt_s[row * 72 + cg * 8] =
                *(const short8*)(K + (size_t)(m0 + row) * 64 + cg * 8);
            *(short8*)&vt_s[row * 72 + cg * 8] =
                *(const short8*)(V + ((size_t)row << 12) + m0 + cg * 8);
        }
        __syncthreads();

        floatx4 s[4];
#pragma unroll
        for (int ms = 0; ms < 4; ++ms) {
            floatx4 acc = {0.f, 0.f, 0.f, 0.f};
            const u16* kp = &kt_s[(ms * 16 + l15) * 72 + quad * 8];
            acc = MFMA16(aq[0], *(const short8*)kp, acc);
            acc = MFMA16(aq[1], *(const short8*)(kp + 32), acc);
            s[ms] = acc;
        }

        // P = exp(S), C-layout -> per-wave LDS [q][m] (intra-wave DS ordering
        // is HW-guaranteed; no barrier needed before own-region read-back)
#pragma unroll
        for (int ms = 0; ms < 4; ++ms)
#pragma unroll
            for (int r = 0; r < 4; ++r)
                p_s[pb + (quad * 4 + r) * 72 + ms * 16 + l15] = f2bf(__expf(s[ms][r]));

        short8 ap0 = *(const short8*)&p_s[pb + l15 * 72 + quad * 8];
        short8 ap1 = *(const short8*)&p_s[pb + l15 * 72 + 32 + quad * 8];
#pragma unroll
        for (int is = 0; is < 4; ++is) {
            const u16* vp = &vt_s[(is * 16 + l15) * 72 + quad * 8];
            oacc[is] = MFMA16(ap0, *(const short8*)vp, oacc[is]);
            oacc[is] = MFMA16(ap1, *(const short8*)(vp + 32), oacc[is]);
        }
        {
            const u16* vp4 = &vt_s[(64 + l15) * 72 + quad * 8];
            lacc = MFMA16(ap0, *(const short8*)vp4, lacc);
            lacc = MFMA16(ap1, *(const short8*)(vp4 + 32), lacc);
        }
        __syncthreads();
    }

    // write unnormalized partials
#pragma unroll
    for (int is = 0; is < 4; ++is)
#pragma unroll
        for (int r = 0; r < 4; ++r) {
            const int n = q0 + wvi * 16 + quad * 4 + r;
            numo[(size_t)n * 64 + is * 16 + l15] = f2bf(oacc[is][r]);
        }
    if (l15 == 0) {
#pragma unroll
        for (int r = 0; r < 4; ++r)
            deno[q0 + wvi * 16 + quad * 4 + r] = lacc[r];
    }
}

// ---------------------------------------------------------------------------
// K3: fused epilogue + split-K reduce (z splits the E2 c-range).
//   y_br[n][i] = (num[br,0]+num[br,1]) / (den[br,0]+den[br,1])  (in staging)
//   yy[n][io] = bnWl(relu(wWl . y_l)) + y_nl
//   out[c][n] = bnW(relu(wW . yy + bW)) + x
// ---------------------------------------------------------------------------
__global__ __launch_bounds__(256) void k_epi(
    const u16* __restrict__ num, const float* __restrict__ den,
    const float* __restrict__ wWl, const float* __restrict__ gWl, const float* __restrict__ betaWl,
    const float* __restrict__ wW, const float* __restrict__ bW,
    const float* __restrict__ gW, const float* __restrict__ betaW,
    const float* __restrict__ x, float* __restrict__ out)
{
    __shared__ __align__(16) u16 yl_s[64 * 72];
    __shared__ __align__(16) u16 ynl_s[64 * 72];
    __shared__ __align__(16) u16 yy_s[64 * 72];
    const int b = blockIdx.y, n0 = blockIdx.x * 64, rb = blockIdx.z;
    const int t = threadIdx.x, wvi = t >> 6, lane = t & 63;
    const int quad = lane >> 4, l15 = lane & 15;
    const size_t ybase = ((size_t)b << 18) + (size_t)n0 * 64;

    const u16* nl0 = num + ybase;                  // z=0
    const u16* nl1 = num + SZ_P + ybase;           // z=1
    const u16* lo0 = num + 2 * SZ_P + ybase;       // z=2
    const u16* lo1 = num + 3 * SZ_P + ybase;       // z=3
    const float* dnl0 = den + b * 4096 + n0;
    const float* dnl1 = den + 16384 + b * 4096 + n0;
    const float* dlo0 = den + 32768 + b * 4096 + n0;
    const float* dlo1 = den + 49152 + b * 4096 + n0;

#pragma unroll
    for (int ch = t; ch < 512; ch += 256) {
        const int row = ch >> 3, cg = ch & 7;
        const float inl = 1.0f / (dnl0[row] + dnl1[row]);
        const float ilo = 1.0f / (dlo0[row] + dlo1[row]);
        const short8 a0 = *(const short8*)(nl0 + row * 64 + cg * 8);
        const short8 a1 = *(const short8*)(nl1 + row * 64 + cg * 8);
        const short8 c0 = *(const short8*)(lo0 + row * 64 + cg * 8);
        const short8 c1 = *(const short8*)(lo1 + row * 64 + cg * 8);
        short8 ynl8, yl8;
#pragma unroll
        for (int j = 0; j < 8; ++j) {
            ynl8[j] = (short)f2bf((bf2f((u16)a0[j]) + bf2f((u16)a1[j])) * inl);
            yl8[j]  = (short)f2bf((bf2f((u16)c0[j]) + bf2f((u16)c1[j])) * ilo);
        }
        *(short8*)&ynl_s[row * 72 + cg * 8] = ynl8;
        *(short8*)&yl_s[row * 72 + cg * 8] = yl8;
    }
    __syncthreads();
    const float rsq = rsqrtf(1.0f + 1e-5f);

    // E1 (both z-halves compute it; 8 MFMAs)
    {
        const short8 a0 = pack8(wWl + (wvi * 16 + l15) * 64 + quad * 8);
        const short8 a1 = pack8(wWl + (wvi * 16 + l15) * 64 + 32 + quad * 8);
        float sc[4], bt[4];
#pragma unroll
        for (int r = 0; r < 4; ++r) {
            const int io = wvi * 16 + quad * 4 + r;
            sc[r] = gWl[io] * rsq;
            bt[r] = betaWl[io];
        }
#pragma unroll
        for (int ns = 0; ns < 4; ++ns) {
            floatx4 acc = {0.f, 0.f, 0.f, 0.f};
            const u16* bp_ = &yl_s[(ns * 16 + l15) * 72 + quad * 8];
            acc = MFMA16(a0, *(const short8*)bp_, acc);
            acc = MFMA16(a1, *(const short8*)(bp_ + 32), acc);
#pragma unroll
            for (int r = 0; r < 4; ++r) {
                const int io = wvi * 16 + quad * 4 + r;
                float val = fmaxf(acc[r], 0.f) * sc[r] + bt[r];
                val += bf2f(ynl_s[(ns * 16 + l15) * 72 + io]);
                yy_s[(ns * 16 + l15) * 72 + io] = f2bf(val);
            }
        }
    }
    __syncthreads();

    // E2: this block's half of the c-range
    {
        const int c0 = rb * 64 + wvi * 16;
        const short8 a0 = pack8(wW + (c0 + l15) * 64 + quad * 8);
        const short8 a1 = pack8(wW + (c0 + l15) * 64 + 32 + quad * 8);
        float bs[4], sc[4], bt[4];
#pragma unroll
        for (int r = 0; r < 4; ++r) {
            const int c = c0 + quad * 4 + r;
            bs[r] = bW[c];
            sc[r] = gW[c] * rsq;
            bt[r] = betaW[c];
        }
#pragma unroll
        for (int ns = 0; ns < 4; ++ns) {
            floatx4 acc = {0.f, 0.f, 0.f, 0.f};
            const u16* bp_ = &yy_s[(ns * 16 + l15) * 72 + quad * 8];
            acc = MFMA16(a0, *(const short8*)bp_, acc);
            acc = MFMA16(a1, *(const short8*)(bp_ + 32), acc);
#pragma unroll
            for (int r = 0; r < 4; ++r) {
                const int c = c0 + quad * 4 + r;
                float val = fmaxf(acc[r] + bs[r], 0.f) * sc[r] + bt[r];
                const size_t xi = ((size_t)b << 19) + ((size_t)c << 12) + n0 + ns * 16 + l15;
                out[xi] = val + x[xi];
            }
        }
    }
}

// ---------------------------------------------------------------------------
extern "C" void kernel_launch(void* const* d_in, const int* in_sizes, int n_in,
                              void* d_out, int out_size, void* d_ws, size_t ws_size,
                              hipStream_t stream) {
    const float* x      = (const float*)d_in[0];
    const float* mask   = (const float*)d_in[1];
    const float* wt_nl  = (const float*)d_in[2];  const float* bt_nl = (const float*)d_in[3];
    const float* wp_nl  = (const float*)d_in[4];  const float* bp_nl = (const float*)d_in[5];
    const float* wt_l   = (const float*)d_in[6];  const float* bt_l  = (const float*)d_in[7];
    const float* wp_l   = (const float*)d_in[8];  const float* bp_l  = (const float*)d_in[9];
    const float* wg_nl  = (const float*)d_in[10]; const float* bg_nl = (const float*)d_in[11];
    const float* wg_l   = (const float*)d_in[12]; const float* bg_l  = (const float*)d_in[13];
    const float* wW     = (const float*)d_in[14]; const float* bW    = (const float*)d_in[15];
    const float* gW     = (const float*)d_in[16]; const float* betaW = (const float*)d_in[17];
    const float* wWl    = (const float*)d_in[18]; const float* gWl   = (const float*)d_in[19];
    const float* betaWl = (const float*)d_in[20];

    // workspace: 6 qkv bufs (12 MB) + num 4 x 2 MB bf16 + den 512 KB = 20.5 MB
    u16* ws  = (u16*)d_ws;
    u16* q0  = ws;            // nl: [B,N,I]
    u16* k0  = q0 + SZ_P;
    u16* v0  = k0 + SZ_P;     // [B,I,N]
    u16* q1  = v0 + SZ_P;     // l
    u16* k1  = q1 + SZ_P;
    u16* v1  = k1 + SZ_P;
    u16* num = v1 + SZ_P;     // 4 x SZ_P bf16 (z-major)
    float* den = (float*)(num + 4 * SZ_P);  // 4 x 16384 fp32

    k_proj<<<dim3(64, 4, 2), 256, 0, stream>>>(x, mask,
        wt_nl, bt_nl, wp_nl, bp_nl, wg_nl, bg_nl,
        wt_l,  bt_l,  wp_l,  bp_l,  wg_l,  bg_l,
        q0, k0, v0, q1, k1, v1);
    k_flash<<<dim3(64, 4, 4), 256, 0, stream>>>(q0, k0, v0, q1, k1, v1, num, den);
    k_epi<<<dim3(64, 4, 2), 256, 0, stream>>>(num, den, wWl, gWl, betaWl,
                                              wW, bW, gW, betaW, x, (float*)d_out);
}